// Round 2
// baseline (243.437 us; speedup 1.0000x reference)
//
#include <hip/hip_runtime.h>

#define NB 8
#define NN 20000
#define NE 640000
#define NF 8
#define NH 128
#define CAP 2048   // max collected in-edges per graph (E/N mean = 32; huge margin)

// ---------------- workspace layout ----------------
// [0,   64)                 : cnt[NB]  (int, padded)
// [64,  64+NB*CAP*4)        : lst[NB][CAP] (int src lists)
// [WS_DEG_OFF, +NB*NN*4)    : deg[NB][NN] (int in-degree)
#define WS_CNT_OFF  0
#define WS_LST_OFF  64
#define WS_DEG_OFF  (64 + NB * CAP * 4)
#define WS_USED     (WS_DEG_OFF + NB * NN * 4)

__global__ void scan_edges(const int* __restrict__ ei,
                           const int* __restrict__ node_idx,
                           int* __restrict__ deg,
                           int* __restrict__ cnt,
                           int* __restrict__ lst) {
    const int  VPG    = NE / 4;                     // int4 vectors per graph (dst half)
    const long total  = (long)NB * VPG;
    const long stride = (long)gridDim.x * blockDim.x;
    for (long g = (long)blockIdx.x * blockDim.x + threadIdx.x; g < total; g += stride) {
        int b = (int)(g / VPG);
        int v = (int)(g - (long)b * VPG);
        const int* dstp = ei + (size_t)b * 2 * NE + NE;   // dst half of graph b
        int4 d = ((const int4*)dstp)[v];                  // coalesced 16B/lane
        int* degb = deg + b * NN;
        atomicAdd(&degb[d.x], 1);
        atomicAdd(&degb[d.y], 1);
        atomicAdd(&degb[d.z], 1);
        atomicAdd(&degb[d.w], 1);
        int tgt = node_idx[b];
        if (d.x == tgt || d.y == tgt || d.z == tgt || d.w == tgt) {  // rare
            const int* srcp = ei + (size_t)b * 2 * NE;
            int e0 = v * 4;
            int dd[4] = {d.x, d.y, d.z, d.w};
#pragma unroll
            for (int c = 0; c < 4; ++c) {
                if (dd[c] == tgt) {
                    int pos = atomicAdd(&cnt[b], 1);
                    if (pos < CAP) lst[b * CAP + pos] = srcp[e0 + c];
                }
            }
        }
    }
}

__global__ __launch_bounds__(NH) void gcn_tail(
    const float* __restrict__ x, const int* __restrict__ node_idx,
    const float* __restrict__ W1, const float* __restrict__ b1,
    const float* __restrict__ W2, const float* __restrict__ b2,
    const float* __restrict__ W3, const float* __restrict__ b3,
    const float* __restrict__ Wl, const float* __restrict__ bl,
    const int* __restrict__ deg, const int* __restrict__ cnt,
    const int* __restrict__ lst, float* __restrict__ out) {
    const int b = blockIdx.x;
    const int j = threadIdx.x;                       // hidden channel 0..127
    const int t = node_idx[b];
    int n = cnt[b]; if (n > CAP) n = CAP;
    const int*   mylst = lst + b * CAP;
    const int*   mydeg = deg + b * NN;
    const float* xb    = x + (size_t)b * NN * NF;

    const float dinv_t = rsqrtf((float)(mydeg[t] + 1));

    // self-loop term: h[t] * dinv_t^2
    float ht = 0.f;
#pragma unroll
    for (int k = 0; k < NF; ++k) ht += xb[(size_t)t * NF + k] * W1[k * NH + j];
    float acc = ht * dinv_t * dinv_t;

    // edge terms: sum over in-edges of the target node
    for (int i = 0; i < n; ++i) {
        int s = mylst[i];
        float dinv_s = rsqrtf((float)(mydeg[s] + 1));
        float hs = 0.f;
#pragma unroll
        for (int k = 0; k < NF; ++k) hs += xb[(size_t)s * NF + k] * W1[k * NH + j];
        acc += hs * (dinv_s * dinv_t);
    }

    __shared__ float h1[NH], h2[NH], h3[NH];
    float v1 = acc + b1[j];
    h1[j] = v1 > 0.f ? v1 : 0.f;
    __syncthreads();

    float a2 = b2[j];
    for (int k = 0; k < NH; ++k) a2 += h1[k] * W2[k * NH + j];
    h2[j] = a2 > 0.f ? a2 : 0.f;
    __syncthreads();

    float a3 = b3[j];
    for (int k = 0; k < NH; ++k) a3 += h2[k] * W3[k * NH + j];
    h3[j] = a3 > 0.f ? a3 : 0.f;
    __syncthreads();

    if (j < 2) {
        float o = bl[j];
        for (int k = 0; k < NH; ++k) o += h3[k] * Wl[k * 2 + j];
        out[b * 2 + j] = o;
    }
}

extern "C" void kernel_launch(void* const* d_in, const int* in_sizes, int n_in,
                              void* d_out, int out_size, void* d_ws, size_t ws_size,
                              hipStream_t stream) {
    const float* x    = (const float*)d_in[0];
    const int*   ei   = (const int*)d_in[1];      // integer inputs arrive as int32
    const int*   nidx = (const int*)d_in[2];
    const float* W1 = (const float*)d_in[3];
    const float* b1 = (const float*)d_in[4];
    const float* W2 = (const float*)d_in[5];
    const float* b2 = (const float*)d_in[6];
    const float* W3 = (const float*)d_in[7];
    const float* b3 = (const float*)d_in[8];
    const float* Wl = (const float*)d_in[9];
    const float* bl = (const float*)d_in[10];
    float* out = (float*)d_out;

    char* ws  = (char*)d_ws;
    int*  cnt = (int*)(ws + WS_CNT_OFF);
    int*  lst = (int*)(ws + WS_LST_OFF);
    int*  deg = (int*)(ws + WS_DEG_OFF);

    hipMemsetAsync(d_ws, 0, WS_USED, stream);

    scan_edges<<<2048, 256, 0, stream>>>(ei, nidx, deg, cnt, lst);

    gcn_tail<<<NB, NH, 0, stream>>>(x, nidx, W1, b1, W2, b2, W3, b3, Wl, bl,
                                    deg, cnt, lst, out);
}

// Round 3
// 50.843 us; speedup vs baseline: 4.7881x; 4.7881x over previous
//
#include <hip/hip_runtime.h>

#define NB 8
#define NN 20000
#define NE 640000
#define NF 8
#define NH 128
#define CAP 2048          // max collected in-edges per graph (mean 32; huge margin)
#define VPG (NE / 4)      // int4 vectors per graph (dst half) = 160000
#define WPG 64            // workgroups per graph in count pass
#define BMW ((NN + 31) / 32)  // bitmap words = 625

// ---------------- workspace layout ----------------
// [0,   64)                 : cnt[NB]  (int, padded)
// [64,  64+NB*CAP*4)        : lst[NB][CAP] (int src lists)
// [WS_DEG_OFF, +NB*NN*4)    : deg[NB][NN] (only tracked entries ever written)
#define WS_CNT_OFF  0
#define WS_LST_OFF  64
#define WS_DEG_OFF  (64 + NB * CAP * 4)
#define WS_USED     (WS_DEG_OFF + NB * NN * 4)

// Pass 1: pure scan of dst stream; collect srcs of edges into the target.
__global__ void collect_edges(const int* __restrict__ ei,
                              const int* __restrict__ node_idx,
                              int* __restrict__ cnt,
                              int* __restrict__ lst) {
    const long total  = (long)NB * VPG;
    const long stride = (long)gridDim.x * blockDim.x;
    for (long g = (long)blockIdx.x * blockDim.x + threadIdx.x; g < total; g += stride) {
        int b = (int)(g / VPG);
        int v = (int)(g - (long)b * VPG);
        const int* dstp = ei + (size_t)b * 2 * NE + NE;
        int4 d = ((const int4*)dstp)[v];                  // coalesced 16B/lane
        int tgt = node_idx[b];
        if (d.x == tgt || d.y == tgt || d.z == tgt || d.w == tgt) {  // ~32/graph
            const int* srcp = ei + (size_t)b * 2 * NE;
            int e0 = v * 4;
            int dd[4] = {d.x, d.y, d.z, d.w};
#pragma unroll
            for (int c = 0; c < 4; ++c) {
                if (dd[c] == tgt) {
                    int pos = atomicAdd(&cnt[b], 1);
                    if (pos < CAP) lst[b * CAP + pos] = srcp[e0 + c];
                }
            }
        }
    }
}

// Pass 2: rescan dst stream; count in-degree ONLY for tracked nodes
// (target + collected srcs) via an LDS bitmap filter. Global atomics are
// issued only on bitmap hits (~0.16% of edges).
__global__ __launch_bounds__(256) void count_deg(
    const int* __restrict__ ei, const int* __restrict__ node_idx,
    const int* __restrict__ cnt, const int* __restrict__ lst,
    int* __restrict__ deg) {
    const int b = blockIdx.x / WPG;
    const int w = blockIdx.x % WPG;
    const int tid = threadIdx.x;

    __shared__ unsigned bm[BMW];
    for (int i = tid; i < BMW; i += 256) bm[i] = 0u;
    __syncthreads();

    const int tgt = node_idx[b];
    int n = cnt[b]; if (n > CAP) n = CAP;
    for (int i = tid; i < n + 1; i += 256) {
        int node = (i == n) ? tgt : lst[b * CAP + i];
        atomicOr(&bm[node >> 5], 1u << (node & 31));
    }
    __syncthreads();

    const int* dstp = ei + (size_t)b * 2 * NE + NE;
    int* degb = deg + b * NN;
    const int per_wg = VPG / WPG;                 // 2500
    const int start = w * per_wg;
    for (int v = start + tid; v < start + per_wg; v += 256) {
        int4 d = ((const int4*)dstp)[v];
        if ((bm[d.x >> 5] >> (d.x & 31)) & 1u) atomicAdd(&degb[d.x], 1);
        if ((bm[d.y >> 5] >> (d.y & 31)) & 1u) atomicAdd(&degb[d.y], 1);
        if ((bm[d.z >> 5] >> (d.z & 31)) & 1u) atomicAdd(&degb[d.z], 1);
        if ((bm[d.w >> 5] >> (d.w & 31)) & 1u) atomicAdd(&degb[d.w], 1);
    }
}

__global__ __launch_bounds__(NH) void gcn_tail(
    const float* __restrict__ x, const int* __restrict__ node_idx,
    const float* __restrict__ W1, const float* __restrict__ b1,
    const float* __restrict__ W2, const float* __restrict__ b2,
    const float* __restrict__ W3, const float* __restrict__ b3,
    const float* __restrict__ Wl, const float* __restrict__ bl,
    const int* __restrict__ deg, const int* __restrict__ cnt,
    const int* __restrict__ lst, float* __restrict__ out) {
    const int b = blockIdx.x;
    const int j = threadIdx.x;                       // hidden channel 0..127
    const int t = node_idx[b];
    int n = cnt[b]; if (n > CAP) n = CAP;
    const int*   mylst = lst + b * CAP;
    const int*   mydeg = deg + b * NN;
    const float* xb    = x + (size_t)b * NN * NF;

    const float dinv_t = rsqrtf((float)(mydeg[t] + 1));

    // self-loop term: h[t] * dinv_t^2
    float ht = 0.f;
#pragma unroll
    for (int k = 0; k < NF; ++k) ht += xb[(size_t)t * NF + k] * W1[k * NH + j];
    float acc = ht * dinv_t * dinv_t;

    // edge terms: sum over in-edges of the target node
    for (int i = 0; i < n; ++i) {
        int s = mylst[i];
        float dinv_s = rsqrtf((float)(mydeg[s] + 1));
        float hs = 0.f;
#pragma unroll
        for (int k = 0; k < NF; ++k) hs += xb[(size_t)s * NF + k] * W1[k * NH + j];
        acc += hs * (dinv_s * dinv_t);
    }

    __shared__ float h1[NH], h2[NH], h3[NH];
    float v1 = acc + b1[j];
    h1[j] = v1 > 0.f ? v1 : 0.f;
    __syncthreads();

    float a2 = b2[j];
    for (int k = 0; k < NH; ++k) a2 += h1[k] * W2[k * NH + j];
    h2[j] = a2 > 0.f ? a2 : 0.f;
    __syncthreads();

    float a3 = b3[j];
    for (int k = 0; k < NH; ++k) a3 += h2[k] * W3[k * NH + j];
    h3[j] = a3 > 0.f ? a3 : 0.f;
    __syncthreads();

    if (j < 2) {
        float o = bl[j];
        for (int k = 0; k < NH; ++k) o += h3[k] * Wl[k * 2 + j];
        out[b * 2 + j] = o;
    }
}

extern "C" void kernel_launch(void* const* d_in, const int* in_sizes, int n_in,
                              void* d_out, int out_size, void* d_ws, size_t ws_size,
                              hipStream_t stream) {
    const float* x    = (const float*)d_in[0];
    const int*   ei   = (const int*)d_in[1];      // integer inputs arrive as int32
    const int*   nidx = (const int*)d_in[2];
    const float* W1 = (const float*)d_in[3];
    const float* b1 = (const float*)d_in[4];
    const float* W2 = (const float*)d_in[5];
    const float* b2 = (const float*)d_in[6];
    const float* W3 = (const float*)d_in[7];
    const float* b3 = (const float*)d_in[8];
    const float* Wl = (const float*)d_in[9];
    const float* bl = (const float*)d_in[10];
    float* out = (float*)d_out;

    char* ws  = (char*)d_ws;
    int*  cnt = (int*)(ws + WS_CNT_OFF);
    int*  lst = (int*)(ws + WS_LST_OFF);
    int*  deg = (int*)(ws + WS_DEG_OFF);

    hipMemsetAsync(d_ws, 0, WS_USED, stream);

    collect_edges<<<2048, 256, 0, stream>>>(ei, nidx, cnt, lst);

    count_deg<<<NB * WPG, 256, 0, stream>>>(ei, nidx, cnt, lst, deg);

    gcn_tail<<<NB, NH, 0, stream>>>(x, nidx, W1, b1, W2, b2, W3, b3, Wl, bl,
                                    deg, cnt, lst, out);
}

// Round 4
// 50.666 us; speedup vs baseline: 4.8048x; 1.0035x over previous
//
#include <hip/hip_runtime.h>

#define NB 8
#define NN 20000
#define NE 640000
#define NF 8
#define NH 128
#define CAP 2048          // max collected in-edges per graph (mean 32; huge margin)
#define VPG (NE / 4)      // int4 vectors per graph (dst half) = 160000
#define WPG 64            // workgroups per graph in count pass
#define BMW ((NN + 31) / 32)  // bitmap words = 625

// ---------------- workspace layout ----------------
// [0,   64)                 : cnt[NB]  (int, padded)
// [64,  64+NB*CAP*4)        : lst[NB][CAP] (int src lists)
// [WS_DEG_OFF, +NB*NN*4)    : deg[NB][NN] (ONLY tracked entries ever written/read;
//                             zeroed lazily by collect_edges, never memset)
#define WS_CNT_OFF  0
#define WS_LST_OFF  64
#define WS_DEG_OFF  (64 + NB * CAP * 4)

// Tiny init: zero the 8 counters and the target's deg slot (covers n==0 case).
__global__ void zero_cnt(const int* __restrict__ node_idx,
                         int* __restrict__ cnt, int* __restrict__ deg) {
    int b = threadIdx.x;
    if (b < NB) {
        cnt[b] = 0;
        deg[b * NN + node_idx[b]] = 0;
    }
}

// Pass 1: scan dst stream; collect srcs of edges into the target, and
// lazily zero the deg slots of every tracked node (plain stores -> visible
// to the next kernel at the kernel boundary).
__global__ void collect_edges(const int* __restrict__ ei,
                              const int* __restrict__ node_idx,
                              int* __restrict__ cnt,
                              int* __restrict__ lst,
                              int* __restrict__ deg) {
    const long total  = (long)NB * VPG;
    const long stride = (long)gridDim.x * blockDim.x;
    for (long g = (long)blockIdx.x * blockDim.x + threadIdx.x; g < total; g += stride) {
        int b = (int)(g / VPG);
        int v = (int)(g - (long)b * VPG);
        const int* dstp = ei + (size_t)b * 2 * NE + NE;
        int4 d = ((const int4*)dstp)[v];                  // coalesced 16B/lane
        int tgt = node_idx[b];
        if (d.x == tgt || d.y == tgt || d.z == tgt || d.w == tgt) {  // ~32/graph
            const int* srcp = ei + (size_t)b * 2 * NE;
            int e0 = v * 4;
            int dd[4] = {d.x, d.y, d.z, d.w};
#pragma unroll
            for (int c = 0; c < 4; ++c) {
                if (dd[c] == tgt) {
                    int pos = atomicAdd(&cnt[b], 1);
                    int s = srcp[e0 + c];
                    if (pos < CAP) lst[b * CAP + pos] = s;
                    deg[b * NN + s] = 0;       // lazy zero of tracked slot
                }
            }
        }
    }
}

// Pass 2: rescan dst stream; count in-degree ONLY for tracked nodes
// (target + collected srcs) via an LDS bitmap filter. Global atomics are
// issued only on bitmap hits (~0.16% of edges).
__global__ __launch_bounds__(256) void count_deg(
    const int* __restrict__ ei, const int* __restrict__ node_idx,
    const int* __restrict__ cnt, const int* __restrict__ lst,
    int* __restrict__ deg) {
    const int b = blockIdx.x / WPG;
    const int w = blockIdx.x % WPG;
    const int tid = threadIdx.x;

    __shared__ unsigned bm[BMW];
    for (int i = tid; i < BMW; i += 256) bm[i] = 0u;
    __syncthreads();

    const int tgt = node_idx[b];
    int n = cnt[b]; if (n > CAP) n = CAP;
    for (int i = tid; i < n + 1; i += 256) {
        int node = (i == n) ? tgt : lst[b * CAP + i];
        atomicOr(&bm[node >> 5], 1u << (node & 31));
    }
    __syncthreads();

    const int* dstp = ei + (size_t)b * 2 * NE + NE;
    int* degb = deg + b * NN;
    const int per_wg = VPG / WPG;                 // 2500
    const int start = w * per_wg;
    for (int v = start + tid; v < start + per_wg; v += 256) {
        int4 d = ((const int4*)dstp)[v];
        if ((bm[d.x >> 5] >> (d.x & 31)) & 1u) atomicAdd(&degb[d.x], 1);
        if ((bm[d.y >> 5] >> (d.y & 31)) & 1u) atomicAdd(&degb[d.y], 1);
        if ((bm[d.z >> 5] >> (d.z & 31)) & 1u) atomicAdd(&degb[d.z], 1);
        if ((bm[d.w >> 5] >> (d.w & 31)) & 1u) atomicAdd(&degb[d.w], 1);
    }
}

__global__ __launch_bounds__(NH) void gcn_tail(
    const float* __restrict__ x, const int* __restrict__ node_idx,
    const float* __restrict__ W1, const float* __restrict__ b1,
    const float* __restrict__ W2, const float* __restrict__ b2,
    const float* __restrict__ W3, const float* __restrict__ b3,
    const float* __restrict__ Wl, const float* __restrict__ bl,
    const int* __restrict__ deg, const int* __restrict__ cnt,
    const int* __restrict__ lst, float* __restrict__ out) {
    const int b = blockIdx.x;
    const int j = threadIdx.x;                       // hidden channel 0..127
    const int t = node_idx[b];
    int n = cnt[b]; if (n > CAP) n = CAP;
    const int*   mylst = lst + b * CAP;
    const int*   mydeg = deg + b * NN;
    const float* xb    = x + (size_t)b * NN * NF;

    const float dinv_t = rsqrtf((float)(mydeg[t] + 1));

    // self-loop term: h[t] * dinv_t^2
    float ht = 0.f;
#pragma unroll
    for (int k = 0; k < NF; ++k) ht += xb[(size_t)t * NF + k] * W1[k * NH + j];
    float acc = ht * dinv_t * dinv_t;

    // edge terms: sum over in-edges of the target node
    for (int i = 0; i < n; ++i) {
        int s = mylst[i];
        float dinv_s = rsqrtf((float)(mydeg[s] + 1));
        float hs = 0.f;
#pragma unroll
        for (int k = 0; k < NF; ++k) hs += xb[(size_t)s * NF + k] * W1[k * NH + j];
        acc += hs * (dinv_s * dinv_t);
    }

    __shared__ float h1[NH], h2[NH], h3[NH];
    float v1 = acc + b1[j];
    h1[j] = v1 > 0.f ? v1 : 0.f;
    __syncthreads();

    float a2 = b2[j];
    for (int k = 0; k < NH; ++k) a2 += h1[k] * W2[k * NH + j];
    h2[j] = a2 > 0.f ? a2 : 0.f;
    __syncthreads();

    float a3 = b3[j];
    for (int k = 0; k < NH; ++k) a3 += h2[k] * W3[k * NH + j];
    h3[j] = a3 > 0.f ? a3 : 0.f;
    __syncthreads();

    if (j < 2) {
        float o = bl[j];
        for (int k = 0; k < NH; ++k) o += h3[k] * Wl[k * 2 + j];
        out[b * 2 + j] = o;
    }
}

extern "C" void kernel_launch(void* const* d_in, const int* in_sizes, int n_in,
                              void* d_out, int out_size, void* d_ws, size_t ws_size,
                              hipStream_t stream) {
    const float* x    = (const float*)d_in[0];
    const int*   ei   = (const int*)d_in[1];      // integer inputs arrive as int32
    const int*   nidx = (const int*)d_in[2];
    const float* W1 = (const float*)d_in[3];
    const float* b1 = (const float*)d_in[4];
    const float* W2 = (const float*)d_in[5];
    const float* b2 = (const float*)d_in[6];
    const float* W3 = (const float*)d_in[7];
    const float* b3 = (const float*)d_in[8];
    const float* Wl = (const float*)d_in[9];
    const float* bl = (const float*)d_in[10];
    float* out = (float*)d_out;

    char* ws  = (char*)d_ws;
    int*  cnt = (int*)(ws + WS_CNT_OFF);
    int*  lst = (int*)(ws + WS_LST_OFF);
    int*  deg = (int*)(ws + WS_DEG_OFF);

    zero_cnt<<<1, 64, 0, stream>>>(nidx, cnt, deg);

    collect_edges<<<2048, 256, 0, stream>>>(ei, nidx, cnt, lst, deg);

    count_deg<<<NB * WPG, 256, 0, stream>>>(ei, nidx, cnt, lst, deg);

    gcn_tail<<<NB, NH, 0, stream>>>(x, nidx, W1, b1, W2, b2, W3, b3, Wl, bl,
                                    deg, cnt, lst, out);
}